// Round 5
// baseline (325.409 us; speedup 1.0000x reference)
//
#include <hip/hip_runtime.h>

// ProbabilityMatrix: 4x row-histogram of per-patch popcounts, normalized.
// ws layout (ints) == out layout (floats), flat concat:
//   box0 [16][16] @ 0, box1 [16][64] @ 256, box2 [16][16] @ 1280, box3 [16][64] @ 1536

#define P_PATCH 32768
#define B_ROWS  16

// DPP-based partial add (pure VALU). quad_perm[1,0,3,2]=0xB1 (xor1),
// quad_perm[2,3,0,1]=0x4E (xor2), row_ror:4=0x124, row_ror:8=0x128.
template <int CTRL>
__device__ __forceinline__ float dpp_add(float s) {
    int t = __builtin_amdgcn_update_dpp(0, __float_as_int(s), CTRL, 0xF, 0xF, true);
    return s + __int_as_float(t);
}

// async global->LDS DMA, 16 B/lane, 1 KB per wave-instr. No VGPR dest; vmcnt-tracked.
__device__ __forceinline__ void dma1k(const float4* g, float4* l) {
    __builtin_amdgcn_global_load_lds((const __attribute__((address_space(1))) void*)g,
                                     (__attribute__((address_space(3))) void*)l,
                                     16, 0, 0);
}

// FV = float4 per patch (4 or 16). Blocks are partitioned by row: row is
// wave-uniform, so the LDS histogram is just S2 bins x 4 per-wave copies.
template <int FV>
__device__ __forceinline__ void hist_box(const float4* __restrict__ in,
                                         int* __restrict__ gcounts,
                                         int block_rank, int blocks_per_box,
                                         float4* ring_all, int* hist) {
    constexpr int S2  = FV * 4;
    constexpr int HP  = S2 + 1;            // padded copy stride (bank stagger)
    constexpr int D   = 4;                 // ring depth (tiles), power of 2
    constexpr int TF4 = 128;               // float4 per tile (2 KB)

    const int tid  = (int)threadIdx.x;
    const int lane = tid & 63;
    const int wid  = tid >> 6;

    const int bpr    = blocks_per_box >> 4;            // blocks per row
    const int row    = block_rank / bpr;
    const int wr     = (block_rank % bpr) * 4 + wid;   // wave rank within row
    const int stride = bpr * 4;                        // waves per row
    const int TPR    = (P_PATCH * FV) / TF4;           // tiles per row (1024 / 4096)
    const float4* rowbase = in + (size_t)row * (P_PATCH * FV);

    float4* ring = ring_all + wid * (D * TF4);         // per-wave 8 KB ring
    int*    h    = hist + wid * HP;                    // per-wave histogram copy

    for (int b = tid; b < 4 * HP; b += 256) hist[b] = 0;
    __syncthreads();

    const int niter = (TPR - wr + stride - 1) / stride;   // wave-uniform, >=1

    // prefill the ring: up to D tiles, 2 DMA instrs each
#pragma unroll
    for (int d = 0; d < D; ++d) {
        if (d < niter) {
            const float4* g = rowbase + (size_t)(wr + d * stride) * TF4 + lane;
            float4* l = ring + d * TF4 + lane;
            dma1k(g, l);
            dma1k(g + 64, l + 64);
        }
    }

    int slot = 0;
    for (int i = 0; i < niter; ++i) {
        const int R = (niter - i < D) ? (niter - i) : D;  // tiles in flight (uniform)
        // wait until the oldest tile's 2 DMAs have landed in LDS
        switch (R) {
            case 4:  asm volatile("s_waitcnt vmcnt(6)" ::: "memory"); break;
            case 3:  asm volatile("s_waitcnt vmcnt(4)" ::: "memory"); break;
            case 2:  asm volatile("s_waitcnt vmcnt(2)" ::: "memory"); break;
            default: asm volatile("s_waitcnt vmcnt(0)" ::: "memory"); break;
        }

        float4* l = ring + slot * TF4;
        float s01[2];
#pragma unroll
        for (int k = 0; k < 2; ++k) {
            float4 v = l[k * 64 + lane];               // ds_read_b128, coalesced
            float x = (v.x + v.y) + (v.z + v.w);
            x = dpp_add<0xB1>(x);
            x = dpp_add<0x4E>(x);                      // quad sums
            if (FV == 16) {
                x = dpp_add<0x124>(x);
                x = dpp_add<0x128>(x);                 // 16-lane sum
            }
            s01[k] = x;
        }

        if ((lane & (FV - 1)) == 0) {                  // patch leaders
#pragma unroll
            for (int k = 0; k < 2; ++k) {
                int b = (int)(s01[k] + 0.5f);          // exact: sum of 0/1 floats
                if (b < S2) atomicAdd(&h[b], 1);       // drop popcount==S2 (TF semantics)
            }
        }

        // refill freed slot with tile i+D
        if (i + D < niter) {
            const float4* g = rowbase + (size_t)(wr + (i + D) * stride) * TF4 + lane;
            float4* ld = ring + slot * TF4 + lane;
            dma1k(g, ld);
            dma1k(g + 64, ld + 64);
        }
        slot = (slot + 1) & (D - 1);
    }
    __syncthreads();

    for (int b = tid; b < S2; b += 256) {
        int c = hist[b] + hist[HP + b] + hist[2 * HP + b] + hist[3 * HP + b];
        if (c) atomicAdd(&gcounts[row * S2 + b], c);
    }
}

#define NB0 128   // 8 blocks/row for 4x4 boxes
#define NB1 384   // 24 blocks/row for 8x8 boxes
// grid = 2*(NB0+NB1) = 1024 blocks = 4 blocks/CU, ~33 KB LDS each -> co-resident

__global__ __launch_bounds__(256, 4) void hist_kernel(const float4* __restrict__ in0,
                                                      const float4* __restrict__ in1,
                                                      const float4* __restrict__ in2,
                                                      const float4* __restrict__ in3,
                                                      int* __restrict__ ws) {
    __shared__ float4 ring[4 * 4 * 128];   // 4 waves x D=4 x 2 KB = 32 KB
    __shared__ int    hist[4 * 65];        // 4 wave-copies, padded (FV=16 worst)
    const int bid = blockIdx.x;
    if (bid < NB0)              hist_box<4 >(in0, ws + 0,    bid,               NB0, ring, hist);
    else if (bid < NB0 + NB1)   hist_box<16>(in1, ws + 256,  bid - NB0,         NB1, ring, hist);
    else if (bid < 2*NB0 + NB1) hist_box<4 >(in2, ws + 1280, bid - NB0 - NB1,   NB0, ring, hist);
    else                        hist_box<16>(in3, ws + 1536, bid - 2*NB0 - NB1, NB1, ring, hist);
}

// one 64-lane wave per (box,row): out[v] = counts[v] / rowsum
__global__ __launch_bounds__(64) void norm_kernel(const int* __restrict__ ws,
                                                  float* __restrict__ out) {
    const int row  = blockIdx.x;      // 0..63
    const int lane = threadIdx.x;     // 0..63
    const int box  = row >> 4;
    const int r    = row & 15;
    const int bins = (box & 1) ? 64 : 16;
    int off = (box == 0) ? 0 : (box == 1) ? 256 : (box == 2) ? 1280 : 1536;
    off += r * bins;

    int c = (lane < bins) ? ws[off + lane] : 0;
    int total = c;
#pragma unroll
    for (int d = 32; d > 0; d >>= 1) total += __shfl_down(total, d);
    total = __shfl(total, 0);

    if (lane < bins) out[off + lane] = (float)c / (float)total;
}

extern "C" void kernel_launch(void* const* d_in, const int* in_sizes, int n_in,
                              void* d_out, int out_size, void* d_ws, size_t ws_size,
                              hipStream_t stream) {
    const float4* in0 = (const float4*)d_in[0];  // cd0_box0 [16,32768,4,4]
    const float4* in1 = (const float4*)d_in[1];  // cd0_box1 [16,32768,8,8]
    const float4* in2 = (const float4*)d_in[2];  // cd1_box0 [16,32768,4,4]
    const float4* in3 = (const float4*)d_in[3];  // cd1_box1 [16,32768,8,8]
    int* ws = (int*)d_ws;

    hipMemsetAsync(ws, 0, 2560 * sizeof(int), stream);
    hist_kernel<<<2 * (NB0 + NB1), 256, 0, stream>>>(in0, in1, in2, in3, ws);
    norm_kernel<<<64, 64, 0, stream>>>(ws, (float*)d_out);
}